// Round 6
// baseline (1097.115 us; speedup 1.0000x reference)
//
#include <hip/hip_runtime.h>
#include <stdint.h>

#define NUM_CHARS 128
#define BATCH 8192
#define SEQ 40
#define HIDDEN 256
#define ZDIM 1024 /* 4*HIDDEN */
#define STRIDE_H 264 /* padded bf16 row stride for h in LDS */
#define LKK 2   /* K-slices in LDS (kk 0..1), 64 KB */
#define AKK 3   /* K-slices AGPR-resident (kk 2..4), 24 AGPR/wave */
#define SKK 5   /* first streamed slice (kk 5..15 from L2, 2-deep window) */

typedef __bf16 bf16x8 __attribute__((ext_vector_type(8)));
typedef float floatx16 __attribute__((ext_vector_type(16)));

#define MFMA_AA(acc, af, bf) \
    asm("v_mfma_f32_32x32x16_bf16 %0, %1, %2, %0" : "+a"(acc) : "v"(af), "a"(bf))
#define MFMA_AV(acc, af, bf) \
    asm("v_mfma_f32_32x32x16_bf16 %0, %1, %2, %0" : "+a"(acc) : "v"(af), "v"(bf))
#define PIN_A(x) asm("" : "+a"(x))
#define HAZ_PRE2(a0,a1) \
    asm volatile("s_nop 4" : "+a"(a0), "+a"(a1))
#define HAZ_POST2(a0,a1) \
    asm volatile("s_nop 7\n\ts_nop 7\n\ts_nop 3" : "+a"(a0), "+a"(a1))

__device__ __forceinline__ unsigned short f2bf(float f) {
    union { float f; uint32_t u; } v; v.f = f;
    uint32_t u = v.u;
    u += 0x7FFFu + ((u >> 16) & 1u); // RNE
    return (unsigned short)(u >> 16);
}
__device__ __forceinline__ float bfhi(uint32_t u) {
    union { uint32_t u; float f; } v; v.u = u & 0xFFFF0000u; return v.f;
}
__device__ __forceinline__ float bflo(uint32_t u) {
    union { uint32_t u; float f; } v; v.u = u << 16; return v.f;
}

// ---- prep kernels (unchanged layouts) ----
// WhFrag[ntile(32)][kk(16)][lane(64)][j(8)] bf16 ; element = Wh[k][n],
// k = kk*16 + (lane>>5)*8 + j, n = ntile*32 + (lane&31)
__global__ void prep_wh(const float* __restrict__ Wh, unsigned short* __restrict__ out) {
    int idx = blockIdx.x * blockDim.x + threadIdx.x;
    int j = idx & 7;
    int lane = (idx >> 3) & 63;
    int kk = (idx >> 9) & 15;
    int ntile = idx >> 13;
    int k = kk * 16 + ((lane >> 5) << 3) + j;
    int n = (ntile << 5) + (lane & 31);
    out[idx] = f2bf(Wh[k * ZDIM + n]);
}

// WxBp[v][c(256)][g(4)] bf16: 4 gate values per (v,c) = one 8-B load
__global__ void prep_wxb(const float* __restrict__ Wx, const float* __restrict__ b,
                         unsigned short* __restrict__ out) {
    int idx = blockIdx.x * blockDim.x + threadIdx.x;
    int v = idx >> 10;
    int r = idx & 1023;
    int c = r >> 2, g = r & 3;
    int src = (g << 8) + c;
    out[idx] = f2bf(Wx[(v << 10) + src] + b[src]);
}

// WdFrag[ntile(4)][kk(16)][lane(64)][j(8)] bf16 ; element = Wd[k][n]
__global__ void prep_wd(const float* __restrict__ Wd, unsigned short* __restrict__ out) {
    int idx = blockIdx.x * blockDim.x + threadIdx.x;
    int j = idx & 7;
    int lane = (idx >> 3) & 63;
    int kk = (idx >> 9) & 15;
    int nt = idx >> 13;
    int k = kk * 16 + ((lane >> 5) << 3) + j;
    int n = (nt << 5) + (lane & 31);
    out[idx] = f2bf(Wd[k * NUM_CHARS + n]);
}

// ---- main kernel: 256 blocks x 1024 threads (16 waves = 4/SIMD, 32 rows/block).
// Wave v: gate-pair p=v>>3 (0:i,f  1:g,o), h-col group hw=v&7.
// Owns z-tiles (gate 2p, hw) and (gate 2p+1, hw); exchanges partner-half rows
// of z with wave v^8 through fp32 LDS so gate math stays local.
__global__ __launch_bounds__(1024, 4) void lstm_main(
    const int* __restrict__ inputs, const unsigned short* __restrict__ WhFrag,
    const unsigned short* __restrict__ WxBp, const unsigned short* __restrict__ WdFrag,
    const float* __restrict__ bd, float* __restrict__ out)
{
    __shared__ unsigned short whlds[LKK * 32 * 512];  // 64 KB: Wh slices kk=0..1
    __shared__ float zx[4 * 16 * 256];                // 64 KB: z-exchange (fp32)
    __shared__ unsigned short hbuf[32 * STRIDE_H];    // 16.9 KB single-buffered h
    __shared__ int tok[32 * SEQ];                     //  5.1 KB  (total 153 KB)
    float* logit = (float*)&whlds[0];                 // 16 KB epilogue overlay

    const int tid = threadIdx.x;
    const int v = tid >> 6;            // wave 0..15
    const int lane = tid & 63;
    const int p = v >> 3;              // gate-pair: 0 -> (i,f), 1 -> (g,o)
    const int hw = v & 7;              // h-col group
    const int gA = p * 2, gB = p * 2 + 1;
    const int nA = gA * 8 + hw, nB = gB * 8 + hw;
    const int r0 = blockIdx.x * 32;

    for (int i = tid; i < 32 * SEQ; i += 1024) tok[i] = inputs[r0 * SEQ + i];
    for (int i = tid; i < 32 * STRIDE_H; i += 1024) hbuf[i] = 0;
    for (int i = tid; i < LKK * 2048; i += 1024) {
        int kk = i >> 11;
        int r = i & 2047;
        int ntile = r >> 6, l = r & 63;
        ((uint4*)whlds)[i] = *(const uint4*)(WhFrag + (((ntile << 4) + kk) << 9) + l * 8);
    }

    // AGPR-resident B-frags: kk = 2..4 for both owned ntiles (24 AGPRs)
    bf16x8 Ba[2][AKK];
#pragma unroll
    for (int kk = 0; kk < AKK; ++kk) {
        Ba[0][kk] = *(const bf16x8*)(WhFrag + (((nA << 4) + LKK + kk) << 9) + lane * 8);
        Ba[1][kk] = *(const bf16x8*)(WhFrag + (((nB << 4) + LKK + kk) << 9) + lane * 8);
        PIN_A(Ba[0][kk]); PIN_A(Ba[1][kk]);
    }
    const unsigned short* sgbA = WhFrag + nA * 8192 + lane * 8;
    const unsigned short* sgbB = WhFrag + nB * 8192 + lane * 8;

    // row-half index per q (0..7): rh = (q&3) + 8*(q>>2) + 4*(lane>>5); own row = rh + 16p
    int rh[8];
#pragma unroll
    for (int q = 0; q < 8; ++q) rh[q] = (q & 3) + 8 * (q >> 2) + 4 * (lane >> 5);

    float c_st[8];
#pragma unroll
    for (int q = 0; q < 8; ++q) c_st[q] = 0.f;

    const float L2E = 1.4426950408889634f;
    const int abase = (lane & 31) * STRIDE_H + ((lane >> 5) << 3);
    const int col = (hw << 5) + (lane & 31);

    __syncthreads();

#pragma unroll 1
    for (int t = 0; t < SEQ; ++t) {
        // ---- gather Wx[token]+b for own 8 (row,col) pairs; consumed at gate time ----
        uint2 gxp[8];
#pragma unroll
        for (int q = 0; q < 8; ++q) {
            int row = rh[q] + 16 * p;
            int vt = tok[row * SEQ + t];
            gxp[q] = *(const uint2*)(WxBp + (vt << 10) + (col << 2));
        }

        // ---- stream window prologue: kk = SKK, SKK+1 ----
        bf16x8 wv[2][2];
        wv[SKK & 1][0] = *(const bf16x8*)(sgbA + (SKK << 9));
        wv[SKK & 1][1] = *(const bf16x8*)(sgbB + (SKK << 9));
        wv[(SKK + 1) & 1][0] = *(const bf16x8*)(sgbA + ((SKK + 1) << 9));
        wv[(SKK + 1) & 1][1] = *(const bf16x8*)(sgbB + ((SKK + 1) << 9));

        floatx16 accA, accB;
#pragma unroll
        for (int i = 0; i < 16; ++i) { accA[i] = 0.f; accB[i] = 0.f; }
        HAZ_PRE2(accA, accB);

        // ---- kk 0..1: B from LDS ----
#pragma unroll
        for (int kk = 0; kk < LKK; ++kk) {
            bf16x8 af = *(const bf16x8*)(hbuf + abase + kk * 16);
            bf16x8 bA = *(const bf16x8*)(whlds + kk * 16384 + nA * 512 + lane * 8);
            bf16x8 bB = *(const bf16x8*)(whlds + kk * 16384 + nB * 512 + lane * 8);
            MFMA_AV(accA, af, bA);
            MFMA_AV(accB, af, bB);
        }
        // ---- kk 2..4: B from AGPR ----
#pragma unroll
        for (int kk = 0; kk < AKK; ++kk) {
            bf16x8 af = *(const bf16x8*)(hbuf + abase + (LKK + kk) * 16);
            MFMA_AA(accA, af, Ba[0][kk]);
            MFMA_AA(accB, af, Ba[1][kk]);
        }
        // ---- kk 5..15: B streamed from L2, 2-deep rolling window ----
#pragma unroll
        for (int kk = SKK; kk < 16; ++kk) {
            const int s = kk & 1;
            bf16x8 af = *(const bf16x8*)(hbuf + abase + kk * 16);
            MFMA_AV(accA, af, wv[s][0]);
            MFMA_AV(accB, af, wv[s][1]);
            if (kk + 2 < 16) {
                wv[s][0] = *(const bf16x8*)(sgbA + ((kk + 2) << 9));
                wv[s][1] = *(const bf16x8*)(sgbB + ((kk + 2) << 9));
            }
        }
        HAZ_POST2(accA, accB);

        // ---- write partner-half rows of own gates to zx (fp32) ----
#pragma unroll
        for (int q = 0; q < 8; ++q) {
            const int i_out = 8 * (1 - p) + q;   // regs holding partner-half rows
            zx[(gA * 16 + rh[q]) * 256 + col] = accA[i_out];
            zx[(gB * 16 + rh[q]) * 256 + col] = accB[i_out];
        }
        __syncthreads();   // zx ready; all h reads done

        // ---- gates on own 8 (row,col) pairs; partner gates from zx ----
#pragma unroll
        for (int q = 0; q < 8; ++q) {
            const int i_own = 8 * p + q;
            float z0, z1, z2, z3; // gates i,f,g,o
            if (p == 0) {
                z0 = accA[i_own]; z1 = accB[i_own];
                z2 = zx[(2 * 16 + rh[q]) * 256 + col];
                z3 = zx[(3 * 16 + rh[q]) * 256 + col];
            } else {
                z2 = accA[i_own]; z3 = accB[i_own];
                z0 = zx[(0 * 16 + rh[q]) * 256 + col];
                z1 = zx[(1 * 16 + rh[q]) * 256 + col];
            }
            float zi = z0 + bflo(gxp[q].x);
            float zf = z1 + bfhi(gxp[q].x);
            float zg = z2 + bflo(gxp[q].y);
            float zo = z3 + bfhi(gxp[q].y);
            float si = __builtin_amdgcn_rcpf(1.f + __builtin_amdgcn_exp2f(-zi * L2E));
            float sf = __builtin_amdgcn_rcpf(1.f + __builtin_amdgcn_exp2f(-zf * L2E));
            float so = __builtin_amdgcn_rcpf(1.f + __builtin_amdgcn_exp2f(-zo * L2E));
            float tg = 1.f - 2.f * __builtin_amdgcn_rcpf(1.f + __builtin_amdgcn_exp2f(2.f * L2E * zg));
            float c = sf * c_st[q] + si * tg;
            c_st[q] = c;
            float tc = 1.f - 2.f * __builtin_amdgcn_rcpf(1.f + __builtin_amdgcn_exp2f(2.f * L2E * c));
            hbuf[(rh[q] + 16 * p) * STRIDE_H + col] = f2bf(so * tc);
        }
        __syncthreads();   // new h visible; zx free for next step
    }

    // ---- logits = h @ Wd + bd (waves 0..3, vocab n-tile = v); overlay whlds ----
    if (v < 4) {
        floatx16 accd;
        float bdv = bd[(v << 5) + (lane & 31)];
#pragma unroll
        for (int i = 0; i < 16; ++i) accd[i] = bdv;
#pragma unroll
        for (int kk = 0; kk < 16; ++kk) {
            bf16x8 af = *(const bf16x8*)(hbuf + abase + kk * 16);
            bf16x8 bfd = *(const bf16x8*)(WdFrag + ((v * 16 + kk) << 9) + lane * 8);
            accd = __builtin_amdgcn_mfma_f32_32x32x16_bf16(af, bfd, accd, 0, 0, 0);
        }
#pragma unroll
        for (int i = 0; i < 16; ++i) {
            int row = (i & 3) + 8 * (i >> 2) + ((lane >> 5) << 2);
            logit[row * NUM_CHARS + (v << 5) + (lane & 31)] = accd[i];
        }
    }
    __syncthreads();

    // ---- softmax: threads 0..511, 16 per row, 8 cols each ----
    if (tid < 512) {
        int row = tid >> 4;
        int c0 = (tid & 15) << 3;
        float vv[8];
        float m = -1e30f;
#pragma unroll
        for (int q = 0; q < 8; ++q) { vv[q] = logit[row * NUM_CHARS + c0 + q]; m = fmaxf(m, vv[q]); }
#pragma unroll
        for (int off = 1; off < 16; off <<= 1) m = fmaxf(m, __shfl_xor(m, off, 16));
        float s = 0.f;
#pragma unroll
        for (int q = 0; q < 8; ++q) { vv[q] = __builtin_amdgcn_exp2f((vv[q] - m) * L2E); s += vv[q]; }
#pragma unroll
        for (int off = 1; off < 16; off <<= 1) s += __shfl_xor(s, off, 16);
        float inv = __builtin_amdgcn_rcpf(s);
        float* op = out + (size_t)(r0 + row) * NUM_CHARS + c0;
#pragma unroll
        for (int q = 0; q < 8; ++q) op[q] = vv[q] * inv;
    }
}

extern "C" void kernel_launch(void* const* d_in, const int* in_sizes, int n_in,
                              void* d_out, int out_size, void* d_ws, size_t ws_size,
                              hipStream_t stream) {
    const int*   inputs = (const int*)d_in[0];
    const float* Wx = (const float*)d_in[1];
    const float* Wh = (const float*)d_in[2];
    const float* b  = (const float*)d_in[3];
    const float* Wd = (const float*)d_in[4];
    const float* bd = (const float*)d_in[5];
    float* out = (float*)d_out;

    unsigned short* WhFrag = (unsigned short*)d_ws;                         // 512 KB
    unsigned short* WxBp   = (unsigned short*)((char*)d_ws + (512 << 10));  // 256 KB
    unsigned short* WdFrag = (unsigned short*)((char*)d_ws + (768 << 10));  // 64 KB

    prep_wh <<<262144 / 256, 256, 0, stream>>>(Wh, WhFrag);
    prep_wxb<<<131072 / 256, 256, 0, stream>>>(Wx, b, WxBp);
    prep_wd <<< 32768 / 256, 256, 0, stream>>>(Wd, WdFrag);
    lstm_main<<<256, 1024, 0, stream>>>(inputs, WhFrag, WxBp, WdFrag, bd, out);
}